// Round 10
// baseline (156.043 us; speedup 1.0000x reference)
//
#include <hip/hip_runtime.h>

// ChannelAttention fused kernel for MI355X (gfx950), round 14.
// B=4, L=16384, C=128, H=8, hd=16. Tokens M = 65536.
//
// R14 = R12 structure with TILE_M 32 -> 16: HALVE per-wave serial work,
// double the grid (4096 blocks).
//
// Why: 10-round scorecard. Flat/negative: barriers 4->1->0, occupancy
// 26->41%, pipelining, kernel split, TRANS<->VALU, I$ shrink, transpose
// elimination (R13: LDS->shuffles, 64us, reverted). The ONLY moves that
// shifted dur were ~additive in per-wave instruction count (R11 +2.3K
// cyc/wave -> +4us; R12 code cut -> -6us; R13 +100 LDS-pipe ops -> +7us);
// extra TLP never helped. Model: co-scheduled waves run near-lockstep,
// sharing each pipe at the same microphase -> per-SIMD time tracks
// per-wave serial length, not wave count. Never varied: work per wave.
//   - stage A: one m-tile (8 x-loads, 24 MFMAs), acc[6] not acc[2][6]
//   - stage B: 128 exp/thread (was 256); same rolled loop, same order
//   - stage C: 1 m-tile (8 MFMAs); grid 4096; 1 barrier; wave-privacy
//     kept (wave w owns heads 2w,2w+1 for all 16 tokens: 16x2x2=64 lanes)
//   - LDS 16x388x4 + 16x136x2 = 29184 B
// Chip-wide instr total rises ~14% (weight loads amortize over half the
// tokens) -> sharp discriminator:
//   per-wave-dominated:  dur -> 38-46us   -> keep, iterate further down
//   chip-issue-bound:    dur -> 62-68us   -> R15 cuts TOTAL instrs
//   per-block fixed:     dur flat 55-60
// Guards: LDS 29184, VGPR ~48-60, FETCH ~17MB WRITE ~33MB, absmax 0.0078125.

typedef __attribute__((ext_vector_type(8))) short bf16x8;
typedef __attribute__((ext_vector_type(4))) float f32x4;
typedef __attribute__((ext_vector_type(4))) unsigned int u32x4;

#define TILE_M 16
#define QKV_STRIDE_F 388   // fp32 elems per token row (>=384; %8==4 -> 16B aligned rows, spread banks)
#define O_STRIDE 136       // bf16 elems per o row

__device__ __forceinline__ unsigned short f2bf(float f) {
    unsigned int u = __builtin_bit_cast(unsigned int, f);
    u += 0x8000u;                      // round half up (cheap, <=0.5 ulp + tie bias)
    return (unsigned short)(u >> 16);
}
// pack two floats -> packed bf16x2 (lo in low short) in 3 VALU ops
__device__ __forceinline__ unsigned int pkbf(float lo, float hi) {
    unsigned int a = __builtin_bit_cast(unsigned int, lo) + 0x8000u;
    unsigned int b = __builtin_bit_cast(unsigned int, hi) + 0x8000u;
    return __builtin_amdgcn_perm(b, a, 0x07060302u);  // {hi16(b),hi16(a)}
}

__global__ void prep_weights(const float* __restrict__ wqkv,
                             const float* __restrict__ wproj,
                             unsigned short* __restrict__ wqkvT,
                             unsigned short* __restrict__ wprojT) {
    int idx = blockIdx.x * 256 + threadIdx.x;
    if (idx < 384 * 128) {               // wqkvT[n][k] = bf16(wqkv[k][n])
        int n = idx >> 7, k = idx & 127;
        wqkvT[idx] = f2bf(wqkv[k * 384 + n]);
    }
    if (idx < 128 * 128) {               // wprojT[n][k] = bf16(wproj[k][n])
        int n = idx >> 7, k = idx & 127;
        wprojT[idx] = f2bf(wproj[k * 128 + n]);
    }
}

__global__ __launch_bounds__(256, 4) void fused_channel_attn(
    const float* __restrict__ x,
    const unsigned short* __restrict__ wqkvT,
    const float* __restrict__ bqkv,
    const unsigned short* __restrict__ wprojT,
    const float* __restrict__ bproj,
    float* __restrict__ out)
{
    __shared__ __align__(16) float us_f[TILE_M * QKV_STRIDE_F];        // 24832 B
    __shared__ __align__(16) unsigned short us_o[TILE_M * O_STRIDE];   // 4352 B

    const int tid  = threadIdx.x;
    const int lane = tid & 63;
    const int wave = tid >> 6;
    const int col  = lane & 15;   // MFMA C/D col == A row (token) == B col (n)
    const int quad = lane >> 4;
    const long base_tok = (long)blockIdx.x * TILE_M;

    // head-aligned n-tiles: wave w produces q,k,v channel tiles of heads 2w, 2w+1
    int ntile[6];
    ntile[0] = 2 * wave;      ntile[1] = 2 * wave + 1;
    ntile[2] = 8 + 2 * wave;  ntile[3] = 9 + 2 * wave;
    ntile[4] = 16 + 2 * wave; ntile[5] = 17 + 2 * wave;

    // ---- stage A: one m-tile. x fragments, load+pack fused per ks.
    bf16x8 afr[4];
    {
        const float* xrow = x + (base_tok + col) * 128;
#pragma unroll
        for (int ks = 0; ks < 4; ++ks) {
            const float4* p = (const float4*)(xrow + ks * 32 + quad * 8);
            float4 f0 = p[0], f1 = p[1];
            u32x4 a = {pkbf(f0.x, f0.y), pkbf(f0.z, f0.w),
                       pkbf(f1.x, f1.y), pkbf(f1.z, f1.w)};
            afr[ks] = __builtin_bit_cast(bf16x8, a);
        }
    }

    // acc[j][r] = qkv[token quad*4+r][ntile[j]*16 + col]; init = bias
    f32x4 acc[6];
#pragma unroll
    for (int j = 0; j < 6; ++j) {
        float b = bqkv[ntile[j] * 16 + col];
        acc[j] = (f32x4){b, b, b, b};
    }
#pragma unroll
    for (int ks = 0; ks < 4; ++ks) {
        bf16x8 bfr[6];                 // batched: 6 loads in flight
#pragma unroll
        for (int j = 0; j < 6; ++j)
            bfr[j] = *(const bf16x8*)&wqkvT[(ntile[j] * 16 + col) * 128 + ks * 32 + quad * 8];
#pragma unroll
        for (int j = 0; j < 6; ++j)
            acc[j] = __builtin_amdgcn_mfma_f32_16x16x32_bf16(afr[ks], bfr[j], acc[j], 0, 0, 0);
    }

    // ---- transpose: this wave's qkv columns -> LDS fp32 [tok][ch]
#pragma unroll
    for (int j = 0; j < 6; ++j)
#pragma unroll
        for (int r = 0; r < 4; ++r)
            us_f[(quad * 4 + r) * QKV_STRIDE_F + ntile[j] * 16 + col] = acc[j][r];

    // ---- stage B lane roles: (token, head-bit, i-half) within the wave
    const int t    = lane & 15;
    const int hbit = (lane >> 4) & 1;
    const int ih   = lane >> 5;
    const int h    = 2 * wave + hbit;           // head owned by this lane
    const float* qkvrow = us_f + t * QKV_STRIDE_F + h * 16;
    const float sl2e = 0.08838834764831845f * 1.44269504088896340f; // scale*log2(e)

    float4 kv4[4], vv4[4];   // 8 ds_read_b128 (RAW same wave: in-order DS)
#pragma unroll
    for (int c = 0; c < 4; ++c) {
        kv4[c] = ((const float4*)(qkvrow + 128))[c];
        vv4[c] = ((const float4*)(qkvrow + 256))[c];
    }

    // ROLLED stage B: 4 iterations x 2 q-channels; q re-read from LDS
    // (runtime ip never indexes a private array -> no scratch).
    {
        unsigned short* orow = &us_o[t * O_STRIDE + h * 16 + ih * 8];
        const float* qptr = qkvrow + ih * 8;
#pragma unroll 1
        for (int ip = 0; ip < 4; ++ip) {
            float q0 = qptr[ip * 2];       // 2 ds_read_b32, issued together
            float q1 = qptr[ip * 2 + 1];
            float ov0, ov1;
#pragma unroll
            for (int u = 0; u < 2; ++u) {
                float qs = (u ? q1 : q0) * sl2e;
                float den = 0.f, num = 0.f;
#pragma unroll
                for (int c = 0; c < 4; ++c) {
                    float e;
                    e = __builtin_amdgcn_exp2f(qs * kv4[c].x); den += e; num = fmaf(e, vv4[c].x, num);
                    e = __builtin_amdgcn_exp2f(qs * kv4[c].y); den += e; num = fmaf(e, vv4[c].y, num);
                    e = __builtin_amdgcn_exp2f(qs * kv4[c].z); den += e; num = fmaf(e, vv4[c].z, num);
                    e = __builtin_amdgcn_exp2f(qs * kv4[c].w); den += e; num = fmaf(e, vv4[c].w, num);
                }
                float o = num * __builtin_amdgcn_rcpf(den);
                if (u) ov1 = o; else ov0 = o;
            }
            *(unsigned int*)((char*)orow + ip * 4) = pkbf(ov0, ov1);
        }
    }

    __syncthreads();       // the ONE barrier: o (all heads/waves) -> stage C

    // ---- stage C: out = o @ Wproj + b. Wave: 2 n-tiles x 1 m-tile.
    const int nb2 = wave * 2;
    {
        bf16x8 af[4];
#pragma unroll
        for (int ks = 0; ks < 4; ++ks)
            af[ks] = *(const bf16x8*)&us_o[col * O_STRIDE + ks * 32 + quad * 8];
        f32x4 acc2[2];
#pragma unroll
        for (int n = 0; n < 2; ++n) {
            float b = bproj[(nb2 + n) * 16 + col];
            acc2[n] = (f32x4){b, b, b, b};
        }
#pragma unroll
        for (int ks = 0; ks < 4; ++ks) {
            bf16x8 bb[2];
#pragma unroll
            for (int n = 0; n < 2; ++n)
                bb[n] = *(const bf16x8*)&wprojT[((nb2 + n) * 16 + col) * 128 + ks * 32 + quad * 8];
#pragma unroll
            for (int n = 0; n < 2; ++n)
                acc2[n] = __builtin_amdgcn_mfma_f32_16x16x32_bf16(af[ks], bb[n], acc2[n], 0, 0, 0);
        }
#pragma unroll
        for (int n = 0; n < 2; ++n)
#pragma unroll
            for (int r = 0; r < 4; ++r) {
                long tt = base_tok + quad * 4 + r;
                out[tt * 128 + (nb2 + n) * 16 + col] = acc2[n][r];
            }
    }
}

extern "C" void kernel_launch(void* const* d_in, const int* in_sizes, int n_in,
                              void* d_out, int out_size, void* d_ws, size_t ws_size,
                              hipStream_t stream) {
    const float* x     = (const float*)d_in[0];
    const float* wqkv  = (const float*)d_in[1];
    const float* bqkv  = (const float*)d_in[2];
    const float* wproj = (const float*)d_in[3];
    const float* bproj = (const float*)d_in[4];
    float* out = (float*)d_out;

    unsigned short* wqkvT  = (unsigned short*)d_ws;    // 384*128 bf16
    unsigned short* wprojT = wqkvT + 384 * 128;        // 128*128 bf16

    prep_weights<<<192, 256, 0, stream>>>(wqkv, wproj, wqkvT, wprojT);

    const int tokens = in_sizes[0] / 128;              // 65536
    fused_channel_attn<<<tokens / TILE_M, 256, 0, stream>>>(
        x, wqkvT, bqkv, wprojT, bproj, out);
}